// Round 1
// 739.878 us; speedup vs baseline: 1.0623x; 1.0623x over previous
//
#include <hip/hip_runtime.h>
#include <math.h>

#define N_ROWS 16384
#define C_CODES 8192
#define DIM 512
#define I_OFS (N_ROWS * DIM)          // 8,388,608
#define D_OFS (I_OFS + N_ROWS)       // 8,404,992

typedef __bf16 bf16;
typedef bf16 bf16x8 __attribute__((ext_vector_type(8)));
typedef float f32x4 __attribute__((ext_vector_type(4)));

// ---- async global->LDS, 16B per lane. LDS dest must be wave-uniform base + lane*16.
__device__ __forceinline__ void gload16(void* lds, const void* g) {
  __builtin_amdgcn_global_load_lds((__attribute__((address_space(1))) void*)(g),
                                   (__attribute__((address_space(3))) void*)(lds), 16, 0, 0);
}

// ---- Kernel 1: normalize embed rows -> en (fp32) + enb (bf16). One wave per row.
__global__ void norm_embed(const float* __restrict__ embed, float* __restrict__ en,
                           bf16* __restrict__ enb) {
  int wave = threadIdx.x >> 6, lane = threadIdx.x & 63;
  int row = blockIdx.x * 4 + wave;
  const float* src = embed + (size_t)row * DIM;
  float4 v0 = ((const float4*)src)[lane * 2];
  float4 v1 = ((const float4*)src)[lane * 2 + 1];
  float s = v0.x * v0.x + v0.y * v0.y + v0.z * v0.z + v0.w * v0.w +
            v1.x * v1.x + v1.y * v1.y + v1.z * v1.z + v1.w * v1.w;
  for (int m = 1; m < 64; m <<= 1) s += __shfl_xor(s, m, 64);
  float nrm = fmaxf(sqrtf(s), 1e-12f);
  float4 o0, o1;
  o0.x = v0.x / nrm; o0.y = v0.y / nrm; o0.z = v0.z / nrm; o0.w = v0.w / nrm;
  o1.x = v1.x / nrm; o1.y = v1.y / nrm; o1.z = v1.z / nrm; o1.w = v1.w / nrm;
  float* dst = en + (size_t)row * DIM;
  ((float4*)dst)[lane * 2] = o0;
  ((float4*)dst)[lane * 2 + 1] = o1;
  bf16x8 b;
  b[0] = (bf16)o0.x; b[1] = (bf16)o0.y; b[2] = (bf16)o0.z; b[3] = (bf16)o0.w;
  b[4] = (bf16)o1.x; b[5] = (bf16)o1.y; b[6] = (bf16)o1.z; b[7] = (bf16)o1.w;
  *(bf16x8*)(enb + (size_t)row * DIM + lane * 8) = b;
}

// ---- Kernel 2: normalize x rows -> xnb (bf16) + xnorm (fp32 norms). One wave per row.
__global__ void norm_x(const float* __restrict__ x, bf16* __restrict__ xnb,
                       float* __restrict__ xnorm) {
  int wave = threadIdx.x >> 6, lane = threadIdx.x & 63;
  int row = blockIdx.x * 4 + wave;
  const float* src = x + (size_t)row * DIM;
  float4 v0 = ((const float4*)src)[lane * 2];
  float4 v1 = ((const float4*)src)[lane * 2 + 1];
  float s = v0.x * v0.x + v0.y * v0.y + v0.z * v0.z + v0.w * v0.w +
            v1.x * v1.x + v1.y * v1.y + v1.z * v1.z + v1.w * v1.w;
  for (int m = 1; m < 64; m <<= 1) s += __shfl_xor(s, m, 64);
  float nrm = fmaxf(sqrtf(s), 1e-12f);
  if (lane == 0) xnorm[row] = nrm;
  bf16x8 b;
  b[0] = (bf16)(v0.x / nrm); b[1] = (bf16)(v0.y / nrm);
  b[2] = (bf16)(v0.z / nrm); b[3] = (bf16)(v0.w / nrm);
  b[4] = (bf16)(v1.x / nrm); b[5] = (bf16)(v1.y / nrm);
  b[6] = (bf16)(v1.z / nrm); b[7] = (bf16)(v1.w / nrm);
  *(bf16x8*)(xnb + (size_t)row * DIM + lane * 8) = b;
}

// ---- Kernel 3: dist = xn @ en^T, 128x128 tile, BK=32, mfma 16x16x32 bf16.
// Also emits tilemax[row][colblock] = max of that 128-col stripe (for refinement).
#define BM 128
#define BN 128
#define BK 32

__global__ __launch_bounds__(256, 2) void gemm_dist(
    const bf16* __restrict__ xnb, const bf16* __restrict__ enb,
    float* __restrict__ dist, float* __restrict__ tilemax) {
  __shared__ bf16 As[BM * BK];   // [m][k] row-major, k contiguous
  __shared__ bf16 Bs[BN * BK];   // [n][k]
  __shared__ float wmax[2][128];

  int tid = threadIdx.x;
  int cb = blockIdx.x;           // 0..63 col block
  int rb = blockIdx.y;           // 0..127 row block
  int rowBase = rb * BM, colBase = cb * BN;
  int wave = tid >> 6, lane = tid & 63;
  int wr = wave >> 1, wc = wave & 1;
  int row16 = lane & 15, quad = lane >> 4;

  f32x4 acc[4][4];
  f32x4 zero = {0.f, 0.f, 0.f, 0.f};
  for (int i = 0; i < 4; ++i)
    for (int j = 0; j < 4; ++j) acc[i][j] = zero;

  // staging: flat tile bytes, 2 rounds of 256 threads x 16B per operand
  int e0 = tid * 8;              // elements [e0, e0+8)
  int e1 = 2048 + tid * 8;
  int m0 = e0 >> 5, k0 = e0 & 31;
  int m1 = e1 >> 5, k1 = e1 & 31;
  const bf16* ga0 = xnb + (size_t)(rowBase + m0) * DIM + k0;
  const bf16* ga1 = xnb + (size_t)(rowBase + m1) * DIM + k1;
  const bf16* gb0 = enb + (size_t)(colBase + m0) * DIM + k0;
  const bf16* gb1 = enb + (size_t)(colBase + m1) * DIM + k1;

  for (int kt = 0; kt < DIM / BK; ++kt) {
    int ko = kt * BK;
    gload16(&As[e0], ga0 + ko);
    gload16(&As[e1], ga1 + ko);
    gload16(&Bs[e0], gb0 + ko);
    gload16(&Bs[e1], gb1 + ko);
    __syncthreads();
    bf16x8 a[4], b[4];
    for (int i = 0; i < 4; ++i)
      a[i] = *(const bf16x8*)&As[(wr * 64 + i * 16 + row16) * BK + quad * 8];
    for (int j = 0; j < 4; ++j)
      b[j] = *(const bf16x8*)&Bs[(wc * 64 + j * 16 + row16) * BK + quad * 8];
    for (int i = 0; i < 4; ++i)
      for (int j = 0; j < 4; ++j)
        acc[i][j] = __builtin_amdgcn_mfma_f32_16x16x32_bf16(a[i], b[j], acc[i][j], 0, 0, 0);
    __syncthreads();
  }

  // epilogue: write dist. D layout: col = lane&15, row = quad*4 + reg.
  for (int i = 0; i < 4; ++i) {
    int gr = rowBase + wr * 64 + i * 16 + quad * 4;
    for (int j = 0; j < 4; ++j) {
      int gc = colBase + wc * 64 + j * 16 + row16;
      for (int r = 0; r < 4; ++r)
        dist[(size_t)(gr + r) * C_CODES + gc] = acc[i][j][r];
    }
  }

  // per-row max over this 128-col stripe
  for (int i = 0; i < 4; ++i) {
    float rm[4];
    for (int r = 0; r < 4; ++r)
      rm[r] = fmaxf(fmaxf(acc[i][0][r], acc[i][1][r]), fmaxf(acc[i][2][r], acc[i][3][r]));
    for (int m = 1; m < 16; m <<= 1)
      for (int r = 0; r < 4; ++r) rm[r] = fmaxf(rm[r], __shfl_xor(rm[r], m, 64));
    if (row16 == 0)
      for (int r = 0; r < 4; ++r) wmax[wc][wr * 64 + i * 16 + quad * 4 + r] = rm[r];
  }
  __syncthreads();
  if (tid < 128) {
    float m = fmaxf(wmax[0][tid], wmax[1][tid]);
    tilemax[(size_t)(rowBase + tid) * 64 + cb] = m;
  }
}

// ---- Kernel 4: per row — exact fp32 argmax among candidates within EPS of the
// bf16-dist row max, then write idx (as float) + quantize (fp32 gather of en).
// One WAVE per row, fully shuffle/ballot-based: no __syncthreads, no LDS, no
// shared atomics, no candidate cap.
#define EPS 0.01f

__global__ __launch_bounds__(256) void refine(
    const float* __restrict__ x, const float* __restrict__ en,
    const float* __restrict__ xnorm, const float* __restrict__ tilemax,
    const float* __restrict__ dist, float* __restrict__ out) {
  int wave = threadIdx.x >> 6, lane = threadIdx.x & 63;
  int r = blockIdx.x * 4 + wave;

  // threshold = (row max over 64 stripe-maxima) - EPS, via butterfly max
  float tmv = tilemax[(size_t)r * 64 + lane];
  float m = tmv;
#pragma unroll
  for (int s = 1; s < 64; s <<= 1) m = fmaxf(m, __shfl_xor(m, s, 64));
  float T = m - EPS;

  // x row resident in registers (8 floats/lane), reused across all candidates
  const float* xr = x + (size_t)r * DIM;
  float4 xv0 = ((const float4*)xr)[lane * 2];
  float4 xv1 = ((const float4*)xr)[lane * 2 + 1];
  float nrm = xnorm[r];

  const float* drow = dist + (size_t)r * C_CODES;
  float bv = -3.0e38f;
  int bi = 0x7fffffff;

  // stripes that can contain a candidate (wave-uniform mask)
  unsigned long long smask = __ballot(tmv >= T);
  while (smask) {
    int cbB = __builtin_ctzll(smask);
    smask &= smask - 1;
    int base = cbB * 128;
    float v0 = drow[base + lane];
    float v1 = drow[base + 64 + lane];
    unsigned long long b0 = __ballot(v0 >= T);
    unsigned long long b1 = __ballot(v1 >= T);
    // enumerate candidates (wave-uniform masks -> no divergence)
    while (b0 | b1) {
      int c;
      if (b0) {
        int l = __builtin_ctzll(b0); b0 &= b0 - 1; c = base + l;
      } else {
        int l = __builtin_ctzll(b1); b1 &= b1 - 1; c = base + 64 + l;
      }
      const float* er = en + (size_t)c * DIM;
      float4 e0 = ((const float4*)er)[lane * 2];
      float4 e1 = ((const float4*)er)[lane * 2 + 1];
      float d = xv0.x * e0.x + xv0.y * e0.y + xv0.z * e0.z + xv0.w * e0.w +
                xv1.x * e1.x + xv1.y * e1.y + xv1.z * e1.z + xv1.w * e1.w;
#pragma unroll
      for (int s = 1; s < 64; s <<= 1) d += __shfl_xor(d, s, 64);
      float v = d / nrm;  // exact fp32 cosine (en already l2-normalized)
      if (v > bv || (v == bv && c < bi)) { bv = v; bi = c; }
    }
  }

  // outputs: index (as float) + quantize row = en[bi]
  if (lane == 0) out[I_OFS + r] = (float)bi;
  const float* eb = en + (size_t)bi * DIM;
  float4 q0 = ((const float4*)eb)[lane * 2];
  float4 q1 = ((const float4*)eb)[lane * 2 + 1];
  float* orow = out + (size_t)r * DIM;
  ((float4*)orow)[lane * 2] = q0;
  ((float4*)orow)[lane * 2 + 1] = q1;
}

extern "C" void kernel_launch(void* const* d_in, const int* in_sizes, int n_in,
                              void* d_out, int out_size, void* d_ws, size_t ws_size,
                              hipStream_t stream) {
  const float* x = (const float*)d_in[0];      // [16384, 512]
  const float* embed = (const float*)d_in[1];  // [8192, 512]
  float* out = (float*)d_out;
  char* ws = (char*)d_ws;
  // workspace layout (46.2 MB total)
  bf16* enb = (bf16*)(ws);                       //  8,388,608 B
  bf16* xnb = (bf16*)(ws + 8388608);             // 16,777,216 B
  float* en = (float*)(ws + 25165824);           // 16,777,216 B
  float* xnorm = (float*)(ws + 41943040);        //     65,536 B
  float* tilemax = (float*)(ws + 42008576);      //  4,194,304 B

  hipLaunchKernelGGL(norm_embed, dim3(C_CODES / 4), dim3(256), 0, stream, embed, en, enb);
  hipLaunchKernelGGL(norm_x, dim3(N_ROWS / 4), dim3(256), 0, stream, x, xnb, xnorm);
  hipLaunchKernelGGL(gemm_dist, dim3(C_CODES / BN, N_ROWS / BM), dim3(256), 0, stream,
                     xnb, enb, out + D_OFS, tilemax);
  hipLaunchKernelGGL(refine, dim3(N_ROWS / 4), dim3(256), 0, stream,
                     x, en, xnorm, tilemax, out + D_OFS, out);
}